// Round 3
// baseline (332.121 us; speedup 1.0000x reference)
//
#include <hip/hip_runtime.h>
#include <hip/hip_bf16.h>
#include <stdint.h>

// NodeLevelInnerProductDecoder: out[b,v,:,:] = zeropad(Z_b) @ zeropad(Z_b)^T
// B=64 graphs, D=128, MAX_NODES=508, 4 views.
// Input z_nodes: fp32 (R1 NaN forensics). Output: fp32 (R2 forensics: bf16-packed
// writes read back as ~C[2k+1] + zero tail -> absmax 209 = ref-scale).
// Write-BW-bound: 264 MB fp32 out -> ~42 us floor at 6.3 TB/s.

typedef __bf16 v8bf __attribute__((ext_vector_type(8)));
typedef float  v4f  __attribute__((ext_vector_type(4)));

#define TILE  128
#define LDA   136    // staging LDS row stride in ushorts (+8: 16B-aligned, conflict-free)
#define LDC   132    // epilogue LDS row stride in floats (+4: 2-way max, free per m136)
#define NMAX  508
#define DD    128
#define NV    4

__device__ __forceinline__ unsigned short f32_to_bf16_rne(float f) {
    unsigned int u = __builtin_bit_cast(unsigned int, f);
    u = (u + 0x7fffu + ((u >> 16) & 1u)) >> 16;
    return (unsigned short)u;
}

__global__ __launch_bounds__(256, 2)
void adj_gram_kernel(const float* __restrict__ z,
                     const int*   __restrict__ counts,
                     float*       __restrict__ out)
{
    // 69.6 KB LDS -> 2 blocks/CU. Reused as fp32 C-tile (128 x 132 floats = 67.6 KB).
    __shared__ __align__(16) unsigned short sAB[2 * TILE * LDA];
    unsigned short* sA = sAB;
    unsigned short* sB = sAB + TILE * LDA;

    const int blk = blockIdx.x;
    const int b   = blk >> 4;
    const int ti  = (blk >> 2) & 3;
    const int tj  = blk & 3;
    const int i0  = ti * TILE;
    const int j0  = tj * TILE;

    // node_counts: hedge int32 vs int64 (values 256..508 -> int64 high word is 0)
    const bool is64 = (counts[1] == 0);
    int off = 0;
    for (int g = 0; g < b; ++g) off += is64 ? counts[2 * g] : counts[g];
    const int n = is64 ? counts[2 * b] : counts[b];

    const int tid = threadIdx.x;

    // ---- stage A-tile (rows i0..) and B-tile (rows j0..): fp32 load -> bf16 LDS ----
    {
        const int rs = tid >> 5;        // 0..7  row within pass
        const int cs = tid & 31;        // 4-float (16B) segment
        const float* zb = z + (size_t)off * DD;
        #pragma unroll
        for (int p = 0; p < 16; ++p) {
            const int r  = p * 8 + rs;
            const int ga = i0 + r, gb = j0 + r;
            v4f va = (v4f)0.0f, vb = (v4f)0.0f;
            if (ga < n) va = *(const v4f*)(zb + (size_t)ga * DD + cs * 4);
            if (gb < n) vb = *(const v4f*)(zb + (size_t)gb * DD + cs * 4);
            ushort4 pa, pb;
            pa.x = f32_to_bf16_rne(va.x); pa.y = f32_to_bf16_rne(va.y);
            pa.z = f32_to_bf16_rne(va.z); pa.w = f32_to_bf16_rne(va.w);
            pb.x = f32_to_bf16_rne(vb.x); pb.y = f32_to_bf16_rne(vb.y);
            pb.z = f32_to_bf16_rne(vb.z); pb.w = f32_to_bf16_rne(vb.w);
            *(ushort4*)&sA[r * LDA + cs * 4] = pa;   // 8B store, 8B-aligned
            *(ushort4*)&sB[r * LDA + cs * 4] = pb;
        }
    }
    __syncthreads();

    // ---- MFMA: each wave computes a 64x64 quadrant; K = 128 (4 steps of 32) ----
    const int wave = tid >> 6;
    const int lane = tid & 63;
    const int my = (wave >> 1) * 64;
    const int nx = (wave & 1) * 64;
    const int lr = lane & 15;            // A: m-row / B: n-col within 16-tile
    const int lk = (lane >> 4) * 8;      // k sub-offset

    v4f acc[4][4];
    #pragma unroll
    for (int i = 0; i < 4; ++i)
        #pragma unroll
        for (int j = 0; j < 4; ++j) acc[i][j] = (v4f)0.0f;

    #pragma unroll
    for (int ks = 0; ks < 4; ++ks) {
        const int ko = ks * 32 + lk;
        v8bf af[4], bfv[4];
        #pragma unroll
        for (int mt = 0; mt < 4; ++mt)
            af[mt] = *(const v8bf*)&sA[(my + mt * 16 + lr) * LDA + ko];
        #pragma unroll
        for (int nt = 0; nt < 4; ++nt)
            bfv[nt] = *(const v8bf*)&sB[(nx + nt * 16 + lr) * LDA + ko];
        #pragma unroll
        for (int mt = 0; mt < 4; ++mt)
            #pragma unroll
            for (int nt = 0; nt < 4; ++nt)
                acc[mt][nt] = __builtin_amdgcn_mfma_f32_16x16x32_bf16(
                    af[mt], bfv[nt], acc[mt][nt], 0, 0, 0);
    }
    __syncthreads();   // all frag reads done; LDS can be reused for fp32 C

    // ---- repack C (MFMA C layout: col=lane&15, row=(lane>>4)*4+reg) to row-major fp32 ----
    float* sC = (float*)sAB;
    const int crow = (lane >> 4) * 4;
    #pragma unroll
    for (int mt = 0; mt < 4; ++mt) {
        #pragma unroll
        for (int nt = 0; nt < 4; ++nt) {
            #pragma unroll
            for (int r = 0; r < 4; ++r) {
                sC[(my + mt * 16 + crow + r) * LDC + (nx + nt * 16 + lr)] =
                    acc[mt][nt][r];
            }
        }
    }
    __syncthreads();

    // ---- write out: full 16B dwordx4 stores (NMAX%4==0 -> no partial tails), 4 views ----
    const int rs = tid >> 5;     // 0..7
    const int cs = tid & 31;     // 4-float (16B) segment
    const int gc = j0 + cs * 4;
    #pragma unroll
    for (int p = 0; p < 16; ++p) {
        const int r  = p * 8 + rs;
        const int gr = i0 + r;
        if (gr >= NMAX || gc >= NMAX) continue;    // rows/cols 508..511 of last tiles
        const uint4 v = *(const uint4*)&sC[r * LDC + cs * 4];
        const size_t rowbase = (size_t)gr * NMAX + gc;   // multiple of 4 -> 16B aligned
        #pragma unroll
        for (int vv = 0; vv < NV; ++vv) {
            const size_t o = (size_t)(b * NV + vv) * (size_t)(NMAX * NMAX) + rowbase;
            *(uint4*)(out + o) = v;
        }
    }
}

extern "C" void kernel_launch(void* const* d_in, const int* in_sizes, int n_in,
                              void* d_out, int out_size, void* d_ws, size_t ws_size,
                              hipStream_t stream) {
    const float* z      = (const float*)d_in[0];
    const int*   counts = (const int*)d_in[1];
    float*       out    = (float*)d_out;
    // 64 graphs x 16 tiles (4x4 of 128^2 over 508 padded nodes)
    adj_gram_kernel<<<dim3(64 * 16), dim3(256), 0, stream>>>(z, counts, out);
}